// Round 3
// baseline (397.339 us; speedup 1.0000x reference)
//
#include <hip/hip_runtime.h>

// Problem constants
#define BB 4
#define GN 2048
#define DD 256
#define GG (GN * GN)            // 4194304

// d_out float offsets (reference return order, flattened)
#define OFF_E   0u
#define OFF_INT 2097152u        // B*G*D
#define OFF_SP  18874368u       // + B*G*G
#define OFF_RG  35651584u
#define OFF_GP  52428800u
#define OFF_CP  56623104u
#define OFF_L0  69206016u

// Native vector type for nontemporal builtins (HIP_vector_type is rejected).
typedef float nat4 __attribute__((ext_vector_type(4)));

__device__ __forceinline__ void nt_store4(float* p, float4 v) {
  nat4 n = {v.x, v.y, v.z, v.w};
  __builtin_nontemporal_store(n, (nat4*)p);
}
__device__ __forceinline__ float4 nt_load4(const float* p) {
  nat4 n = __builtin_nontemporal_load((const nat4*)p);
  return make_float4(n.x, n.y, n.z, n.w);
}

// ---------------------------------------------------------------------------
// Kernel 1: embedding gather + the two 256-length dots (s_i, s_j).
// One wave (64 lanes) per (b,g) row, 4 rows per 256-thread block.
// ---------------------------------------------------------------------------
__global__ __launch_bounds__(256) void k_embed(
    const int* __restrict__ gene_ids, const float* __restrict__ emb,
    const float* __restrict__ w, float* __restrict__ e_out,
    float* __restrict__ s_i, float* __restrict__ s_j) {
  const int row  = blockIdx.x * 4 + (threadIdx.x >> 6);  // 0 .. B*G-1
  const int lane = threadIdx.x & 63;
  const int gid  = gene_ids[row];

  const float4 v = ((const float4*)(emb + (size_t)gid * DD))[lane];
  nt_store4(e_out + (size_t)row * DD + lane * 4, v);

  const float4 w0 = ((const float4*)w)[lane];          // w_proj[:256]
  const float4 w1 = ((const float4*)(w + DD))[lane];   // w_proj[256:]
  float di = v.x * w0.x + v.y * w0.y + v.z * w0.z + v.w * w0.w;
  float dj = v.x * w1.x + v.y * w1.y + v.z * w1.z + v.w * w1.w;
#pragma unroll
  for (int off = 32; off > 0; off >>= 1) {
    di += __shfl_down(di, off);
    dj += __shfl_down(dj, off);
  }
  if (lane == 0) { s_i[row] = di; s_j[row] = dj; }
}

// ---------------------------------------------------------------------------
// Kernel 2 (fused): per (i, j4) slot —
//   gate_probs, class_probs (one-hot), l0 partial sum, and the three
//   (B,G,G) outputs for all 4 batches. Every global byte touched exactly once.
// ---------------------------------------------------------------------------
__device__ __forceinline__ int argmax3(float a, float b, float c) {
  int idx = 0; float best = a;
  if (b > best) { best = b; idx = 1; }
  if (c > best) { idx = 2; }
  return idx;
}
__device__ __forceinline__ float sigf(float x) { return 1.0f / (1.0f + __expf(-x)); }

__global__ __launch_bounds__(256) void k_fused(
    const float* __restrict__ gl, const float* __restrict__ cl,
    const float* __restrict__ s_i, const float* __restrict__ s_j,
    const float* __restrict__ bptr,
    float* __restrict__ gate_out, float* __restrict__ cp_out,
    float* __restrict__ inter, float* __restrict__ sparse,
    float* __restrict__ reg, float* __restrict__ l0) {
  const int t  = blockIdx.x * 256 + threadIdx.x;  // 0 .. GG/4-1
  const int j4 = t & (GN / 4 - 1);                // 0..511
  const int i  = t >> 9;                          // 0..2047

  const float4 g  = nt_load4(gl + (size_t)t * 4);
  const float4 c0 = nt_load4(cl + (size_t)t * 12);
  const float4 c1 = nt_load4(cl + (size_t)t * 12 + 4);
  const float4 c2 = nt_load4(cl + (size_t)t * 12 + 8);

  const int i0 = argmax3(c0.x, c0.y, c0.z);
  const int i1 = argmax3(c0.w, c1.x, c1.y);
  const int i2 = argmax3(c1.z, c1.w, c2.x);
  const int i3 = argmax3(c2.y, c2.z, c2.w);

  const float gx = g.x > 0.0f ? 1.0f : 0.0f;
  const float gy = g.y > 0.0f ? 1.0f : 0.0f;
  const float gz = g.z > 0.0f ? 1.0f : 0.0f;
  const float gw = g.w > 0.0f ? 1.0f : 0.0f;

  nt_store4(gate_out + (size_t)t * 4, make_float4(gx, gy, gz, gw));
  nt_store4(cp_out + (size_t)t * 12,
            make_float4(i0 == 0, i0 == 1, i0 == 2, i1 == 0));
  nt_store4(cp_out + (size_t)t * 12 + 4,
            make_float4(i1 == 1, i1 == 2, i2 == 0, i2 == 1));
  nt_store4(cp_out + (size_t)t * 12 + 8,
            make_float4(i2 == 2, i3 == 0, i3 == 1, i3 == 2));

  // class value = argmax - 1
  const float vx = (float)(i0 - 1), vy = (float)(i1 - 1);
  const float vz = (float)(i2 - 1), vw = (float)(i3 - 1);
  const float b0 = bptr[0];

#pragma unroll
  for (int b = 0; b < BB; ++b) {
    const float  si = s_i[b * GN + i] + b0;
    const float4 sj = ((const float4*)(s_j + b * GN))[j4];
    const float4 it4 = make_float4(si + sj.x, si + sj.y, si + sj.z, si + sj.w);
    const float4 sp4 = make_float4(it4.x * gx, it4.y * gy, it4.z * gz, it4.w * gw);
    const float4 rg4 = make_float4(sp4.x * vx, sp4.y * vy, sp4.z * vz, sp4.w * vw);
    const size_t o = (size_t)b * (GG / 4) + t;
    nt_store4(inter  + o * 4, it4);
    nt_store4(sparse + o * 4, sp4);
    nt_store4(reg    + o * 4, rg4);
  }

  // l0_reg = sum(sigmoid(gate_logits))
  float s = sigf(g.x) + sigf(g.y) + sigf(g.z) + sigf(g.w);
#pragma unroll
  for (int off = 32; off > 0; off >>= 1) s += __shfl_down(s, off);
  __shared__ float part[4];
  if ((threadIdx.x & 63) == 0) part[threadIdx.x >> 6] = s;
  __syncthreads();
  if (threadIdx.x == 0) atomicAdd(l0, part[0] + part[1] + part[2] + part[3]);
}

extern "C" void kernel_launch(void* const* d_in, const int* in_sizes, int n_in,
                              void* d_out, int out_size, void* d_ws, size_t ws_size,
                              hipStream_t stream) {
  const int*   gene_ids = (const int*)d_in[0];
  const float* emb      = (const float*)d_in[1];
  const float* w        = (const float*)d_in[2];
  const float* bptr     = (const float*)d_in[3];
  const float* gl       = (const float*)d_in[4];
  const float* cl       = (const float*)d_in[5];
  float* out = (float*)d_out;

  float* s_i = (float*)d_ws;        // B*G floats
  float* s_j = s_i + BB * GN;       // B*G floats

  (void)hipMemsetAsync(out + OFF_L0, 0, sizeof(float), stream);  // l0 accumulator

  k_embed<<<BB * GN / 4, 256, 0, stream>>>(gene_ids, emb, w, out + OFF_E, s_i, s_j);
  k_fused<<<GG / 1024, 256, 0, stream>>>(gl, cl, s_i, s_j, bptr,
                                         out + OFF_GP, out + OFF_CP,
                                         out + OFF_INT, out + OFF_SP,
                                         out + OFF_RG, out + OFF_L0);
}

// Round 4
// 373.812 us; speedup vs baseline: 1.0629x; 1.0629x over previous
//
#include <hip/hip_runtime.h>

// Problem constants
#define BB 4
#define GN 2048
#define DD 256
#define GG (GN * GN)            // 4194304

// d_out float offsets (reference return order, flattened)
#define OFF_E   0u
#define OFF_INT 2097152u        // B*G*D
#define OFF_SP  18874368u       // + B*G*G
#define OFF_RG  35651584u
#define OFF_GP  52428800u
#define OFF_CP  56623104u
#define OFF_L0  69206016u

// ---------------------------------------------------------------------------
// Kernel 1: embedding gather + the two 256-length dots (s_i, s_j).
// One wave (64 lanes) per (b,g) row, 4 rows per 256-thread block.
// Thread (0,0) also zeroes the l0 accumulator (stream-ordered before k_fused).
// ---------------------------------------------------------------------------
__global__ __launch_bounds__(256) void k_embed(
    const int* __restrict__ gene_ids, const float* __restrict__ emb,
    const float* __restrict__ w, float* __restrict__ e_out,
    float* __restrict__ s_i, float* __restrict__ s_j, float* __restrict__ l0) {
  if (blockIdx.x == 0 && threadIdx.x == 0) *l0 = 0.0f;

  const int row  = blockIdx.x * 4 + (threadIdx.x >> 6);  // 0 .. B*G-1
  const int lane = threadIdx.x & 63;
  const int gid  = gene_ids[row];

  const float4 v = ((const float4*)(emb + (size_t)gid * DD))[lane];
  ((float4*)(e_out + (size_t)row * DD))[lane] = v;

  const float4 w0 = ((const float4*)w)[lane];          // w_proj[:256]
  const float4 w1 = ((const float4*)(w + DD))[lane];   // w_proj[256:]
  float di = v.x * w0.x + v.y * w0.y + v.z * w0.z + v.w * w0.w;
  float dj = v.x * w1.x + v.y * w1.y + v.z * w1.z + v.w * w1.w;
#pragma unroll
  for (int off = 32; off > 0; off >>= 1) {
    di += __shfl_down(di, off);
    dj += __shfl_down(dj, off);
  }
  if (lane == 0) { s_i[row] = di; s_j[row] = dj; }
}

// ---------------------------------------------------------------------------
// Kernel 2 (fused): per (i, j4) slot — gate_probs, class_probs (one-hot),
// l0 partial sum, and the three (B,G,G) outputs for all 4 batches.
// cl loads and cp stores are staged through LDS so every global access is a
// fully-coalesced 16B/lane stream (the raw layout is 16B @ 48B stride).
// ---------------------------------------------------------------------------
__device__ __forceinline__ int argmax3(float a, float b, float c) {
  int idx = 0; float best = a;
  if (b > best) { best = b; idx = 1; }
  if (c > best) { idx = 2; }
  return idx;
}
__device__ __forceinline__ float sigf(float x) { return 1.0f / (1.0f + __expf(-x)); }

__global__ __launch_bounds__(256) void k_fused(
    const float* __restrict__ gl, const float* __restrict__ cl,
    const float* __restrict__ s_i, const float* __restrict__ s_j,
    const float* __restrict__ bptr,
    float* __restrict__ gate_out, float* __restrict__ cp_out,
    float* __restrict__ inter, float* __restrict__ sparse,
    float* __restrict__ reg, float* __restrict__ l0) {
  __shared__ float4 lds[768];   // 12 KB: block's cl slab, then reused for cp

  const int tid = threadIdx.x;
  const int t   = blockIdx.x * 256 + tid;   // 0 .. GG/4-1
  const int j4  = t & (GN / 4 - 1);         // 0..511
  const int i   = t >> 9;                   // 0..2047
  const size_t clBase = (size_t)blockIdx.x * 768;  // float4 units

  // ---- coalesced cl load -> LDS ----
  const float4* cl4 = (const float4*)cl;
#pragma unroll
  for (int k = 0; k < 3; ++k) lds[tid + k * 256] = cl4[clBase + tid + k * 256];
  __syncthreads();
  const float4 c0 = lds[tid * 3];
  const float4 c1 = lds[tid * 3 + 1];
  const float4 c2 = lds[tid * 3 + 2];

  const int i0 = argmax3(c0.x, c0.y, c0.z);
  const int i1 = argmax3(c0.w, c1.x, c1.y);
  const int i2 = argmax3(c1.z, c1.w, c2.x);
  const int i3 = argmax3(c2.y, c2.z, c2.w);

  // ---- cp one-hots -> LDS -> coalesced store ----
  __syncthreads();
  lds[tid * 3]     = make_float4(i0 == 0, i0 == 1, i0 == 2, i1 == 0);
  lds[tid * 3 + 1] = make_float4(i1 == 1, i1 == 2, i2 == 0, i2 == 1);
  lds[tid * 3 + 2] = make_float4(i2 == 2, i3 == 0, i3 == 1, i3 == 2);
  __syncthreads();
  float4* cp4 = (float4*)cp_out;
#pragma unroll
  for (int k = 0; k < 3; ++k) cp4[clBase + tid + k * 256] = lds[tid + k * 256];

  // ---- gate ----
  const float4 g = ((const float4*)gl)[t];
  const float gx = g.x > 0.0f ? 1.0f : 0.0f;
  const float gy = g.y > 0.0f ? 1.0f : 0.0f;
  const float gz = g.z > 0.0f ? 1.0f : 0.0f;
  const float gw = g.w > 0.0f ? 1.0f : 0.0f;
  ((float4*)gate_out)[t] = make_float4(gx, gy, gz, gw);

  // class value = argmax - 1
  const float vx = (float)(i0 - 1), vy = (float)(i1 - 1);
  const float vz = (float)(i2 - 1), vw = (float)(i3 - 1);
  const float b0 = bptr[0];

  // ---- the three (B,G,G) streams ----
#pragma unroll
  for (int b = 0; b < BB; ++b) {
    const float  si = s_i[b * GN + i] + b0;
    const float4 sj = ((const float4*)(s_j + b * GN))[j4];
    const float4 it4 = make_float4(si + sj.x, si + sj.y, si + sj.z, si + sj.w);
    const float4 sp4 = make_float4(it4.x * gx, it4.y * gy, it4.z * gz, it4.w * gw);
    const float4 rg4 = make_float4(sp4.x * vx, sp4.y * vy, sp4.z * vz, sp4.w * vw);
    const size_t o = (size_t)b * (GG / 4) + t;
    ((float4*)inter)[o]  = it4;
    ((float4*)sparse)[o] = sp4;
    ((float4*)reg)[o]    = rg4;
  }

  // ---- l0_reg = sum(sigmoid(gate_logits)) ----
  float s = sigf(g.x) + sigf(g.y) + sigf(g.z) + sigf(g.w);
#pragma unroll
  for (int off = 32; off > 0; off >>= 1) s += __shfl_down(s, off);
  __shared__ float part[4];
  if ((tid & 63) == 0) part[tid >> 6] = s;
  __syncthreads();
  if (tid == 0) atomicAdd(l0, part[0] + part[1] + part[2] + part[3]);
}

extern "C" void kernel_launch(void* const* d_in, const int* in_sizes, int n_in,
                              void* d_out, int out_size, void* d_ws, size_t ws_size,
                              hipStream_t stream) {
  const int*   gene_ids = (const int*)d_in[0];
  const float* emb      = (const float*)d_in[1];
  const float* w        = (const float*)d_in[2];
  const float* bptr     = (const float*)d_in[3];
  const float* gl       = (const float*)d_in[4];
  const float* cl       = (const float*)d_in[5];
  float* out = (float*)d_out;

  float* s_i = (float*)d_ws;        // B*G floats
  float* s_j = s_i + BB * GN;       // B*G floats

  k_embed<<<BB * GN / 4, 256, 0, stream>>>(gene_ids, emb, w, out + OFF_E,
                                           s_i, s_j, out + OFF_L0);
  k_fused<<<GG / 1024, 256, 0, stream>>>(gl, cl, s_i, s_j, bptr,
                                         out + OFF_GP, out + OFF_CP,
                                         out + OFF_INT, out + OFF_SP,
                                         out + OFF_RG, out + OFF_L0);
}